// Round 1
// baseline (504.683 us; speedup 1.0000x reference)
//
#include <hip/hip_runtime.h>
#include <limits.h>

#define HH 128
#define WW_ 128
#define HW 16384
#define NB 16
#define CF 192
#define H2 64
#define W2 64

// ---------------------------------------------------------------------------
// Kernel 1: one block per image. Union-find CCL (8-connected) in LDS, then
// per-component stats via global atomics (count, conf_sum, bbox, max pixel id).
// ---------------------------------------------------------------------------

__device__ inline int uf_find(int* par, int x) {
    volatile int* vp = (volatile int*)par;
    int p = vp[x];
    while (p != x) {
        int g = vp[p];        // grandparent (chains strictly decrease -> terminates)
        vp[x] = g;            // path halving (writes an ancestor: safe under races)
        x = g;
        p = vp[x];
    }
    return x;
}

__device__ inline void uf_union(int* par, int a, int b) {
    int ra = uf_find(par, a);
    int rb = uf_find(par, b);
    while (ra != rb) {
        if (ra < rb) { int t = ra; ra = rb; rb = t; }   // link larger -> smaller
        int old = atomicCAS(&par[ra], ra, rb);
        if (old == ra) return;
        ra = uf_find(par, old);
        rb = uf_find(par, rb);
    }
}

__global__ __launch_bounds__(1024) void ccl_stats_kernel(
    const float* __restrict__ prob,
    int* __restrict__ cnt, float* __restrict__ conf,
    int* __restrict__ minr, int* __restrict__ maxr,
    int* __restrict__ minc, int* __restrict__ maxc,
    int* __restrict__ maxid)
{
    __shared__ int parent[HW];
    __shared__ unsigned char fgm[HW];
    const int b = blockIdx.x;
    const int tid = threadIdx.x;
    const float* p = prob + (size_t)b * HW;
    const int base = b * HW;

    // init: parent, fg mask, and the global stats slots for this image
    for (int i = tid; i < HW; i += 1024) {
        parent[i] = i;
        fgm[i] = (p[i] > 0.5f) ? 1 : 0;
        cnt[base + i] = 0;
        conf[base + i] = 0.f;
        minr[base + i] = INT_MAX;
        maxr[base + i] = -1;
        minc[base + i] = INT_MAX;
        maxc[base + i] = -1;
        maxid[base + i] = -1;
    }
    __syncthreads();

    // unions with the 4 "previous" 8-neighbors (symmetric closure covers all 8)
    for (int i = tid; i < HW; i += 1024) {
        if (!fgm[i]) continue;
        int r = i >> 7, c = i & 127;
        if (c > 0 && fgm[i - 1]) uf_union(parent, i, i - 1);
        if (r > 0) {
            if (fgm[i - WW_]) uf_union(parent, i, i - WW_);
            if (c > 0 && fgm[i - WW_ - 1]) uf_union(parent, i, i - WW_ - 1);
            if (c < 127 && fgm[i - WW_ + 1]) uf_union(parent, i, i - WW_ + 1);
        }
    }
    __syncthreads();

    // stats: each thread owns 16 contiguous pixels; aggregate runs with the
    // same root locally before flushing atomics (cuts same-address contention)
    const int i0 = tid * 16;
    int curRoot = -1, aCnt = 0, aMinr = 0, aMaxr = 0, aMinc = 0, aMaxc = 0, aMaxid = 0;
    float aConf = 0.f;
    for (int j = 0; j < 16; ++j) {
        int i = i0 + j;
        if (!fgm[i]) continue;
        int root = uf_find(parent, i);
        int r = i >> 7, c = i & 127;
        float pv = p[i];
        if (root == curRoot) {
            aCnt += 1; aConf += pv;
            aMinr = min(aMinr, r); aMaxr = max(aMaxr, r);
            aMinc = min(aMinc, c); aMaxc = max(aMaxc, c);
            aMaxid = i;
        } else {
            if (curRoot >= 0) {
                atomicAdd(&cnt[base + curRoot], aCnt);
                atomicAdd(&conf[base + curRoot], aConf);
                atomicMin(&minr[base + curRoot], aMinr);
                atomicMax(&maxr[base + curRoot], aMaxr);
                atomicMin(&minc[base + curRoot], aMinc);
                atomicMax(&maxc[base + curRoot], aMaxc);
                atomicMax(&maxid[base + curRoot], aMaxid);
            }
            curRoot = root; aCnt = 1; aConf = pv;
            aMinr = aMaxr = r; aMinc = aMaxc = c; aMaxid = i;
        }
    }
    if (curRoot >= 0) {
        atomicAdd(&cnt[base + curRoot], aCnt);
        atomicAdd(&conf[base + curRoot], aConf);
        atomicMin(&minr[base + curRoot], aMinr);
        atomicMax(&maxr[base + curRoot], aMaxr);
        atomicMin(&minc[base + curRoot], aMinc);
        atomicMax(&maxc[base + curRoot], aMaxc);
        atomicMax(&maxid[base + curRoot], aMaxid);
    }
}

// ---------------------------------------------------------------------------
// Kernel 2: one block per image. Find top-3 components by (mean_conf desc,
// segment-id asc), count K, apply duplication rules, write 3 bboxes.
// bbox[b][slot] = (min_r, height, min_c, width); K==0 -> full image.
// ---------------------------------------------------------------------------

__global__ __launch_bounds__(256) void select_kernel(
    const int* __restrict__ cnt, const float* __restrict__ conf,
    const int* __restrict__ minr, const int* __restrict__ maxr,
    const int* __restrict__ minc, const int* __restrict__ maxc,
    const int* __restrict__ maxid,
    int* __restrict__ bbox)
{
    const int b = blockIdx.x;
    const int tid = threadIdx.x;
    const int base = b * HW;

    float s0 = -INFINITY, s1 = -INFINITY, s2 = -INFINITY;
    int id0 = INT_MAX, id1 = INT_MAX, id2 = INT_MAX;
    int r0 = -1, r1 = -1, r2 = -1;
    int myK = 0;

    for (int i = tid; i < HW; i += 256) {
        int c = cnt[base + i];
        if (c <= 0) continue;
        myK++;
        float s = conf[base + i] / (float)c;
        int id = maxid[base + i];
        if (s > s0 || (s == s0 && id < id0)) {
            s2 = s1; id2 = id1; r2 = r1;
            s1 = s0; id1 = id0; r1 = r0;
            s0 = s; id0 = id; r0 = i;
        } else if (s > s1 || (s == s1 && id < id1)) {
            s2 = s1; id2 = id1; r2 = r1;
            s1 = s; id1 = id; r1 = i;
        } else if (s > s2 || (s == s2 && id < id2)) {
            s2 = s; id2 = id; r2 = i;
        }
    }

    __shared__ float ss[256 * 3];
    __shared__ int sid[256 * 3];
    __shared__ int sr[256 * 3];
    __shared__ int sk[256];
    ss[tid * 3 + 0] = s0; sid[tid * 3 + 0] = id0; sr[tid * 3 + 0] = r0;
    ss[tid * 3 + 1] = s1; sid[tid * 3 + 1] = id1; sr[tid * 3 + 1] = r1;
    ss[tid * 3 + 2] = s2; sid[tid * 3 + 2] = id2; sr[tid * 3 + 2] = r2;
    sk[tid] = myK;
    __syncthreads();

    if (tid == 0) {
        float t0 = -INFINITY, t1 = -INFINITY, t2 = -INFINITY;
        int tid0 = INT_MAX, tid1 = INT_MAX, tid2 = INT_MAX;
        int tr0 = -1, tr1 = -1, tr2 = -1;
        int K = 0;
        for (int t = 0; t < 256; ++t) K += sk[t];
        for (int t = 0; t < 256 * 3; ++t) {
            float s = ss[t]; int id = sid[t]; int rr = sr[t];
            if (rr < 0) continue;
            if (s > t0 || (s == t0 && id < tid0)) {
                t2 = t1; tid2 = tid1; tr2 = tr1;
                t1 = t0; tid1 = tid0; tr1 = tr0;
                t0 = s; tid0 = id; tr0 = rr;
            } else if (s > t1 || (s == t1 && id < tid1)) {
                t2 = t1; tid2 = tid1; tr2 = tr1;
                t1 = s; tid1 = id; tr1 = rr;
            } else if (s > t2 || (s == t2 && id < tid2)) {
                t2 = s; tid2 = id; tr2 = rr;
            }
        }
        int roots[3];
        if (K >= 3)      { roots[0] = tr0; roots[1] = tr1; roots[2] = tr2; }
        else if (K == 2) { roots[0] = tr0; roots[1] = tr0; roots[2] = tr1; }
        else             { roots[0] = tr0; roots[1] = tr0; roots[2] = tr0; }
        for (int slot = 0; slot < 3; ++slot) {
            int mr, h, mc, w;
            if (K == 0) { mr = 0; h = HH; mc = 0; w = WW_; }
            else {
                int rt = roots[slot];
                mr = minr[base + rt];
                h  = maxr[base + rt] + 1 - mr;
                mc = minc[base + rt];
                w  = maxc[base + rt] + 1 - mc;
            }
            int* o = bbox + (b * 3 + slot) * 4;
            o[0] = mr; o[1] = h; o[2] = mc; o[3] = w;
        }
    }
}

// ---------------------------------------------------------------------------
// Kernel 3: nearest-neighbor crop-resize gather. One float4 store per thread.
// out[b, slot*192+c, y, x] = feat[b, c, mr + (y*h)>>6, mc + (x*w)>>6]
// ---------------------------------------------------------------------------

__global__ __launch_bounds__(256) void crop_kernel(
    const float* __restrict__ feat, const int* __restrict__ bbox,
    float* __restrict__ out)
{
    const int gid = blockIdx.x * 256 + threadIdx.x;   // 9,437,184 total
    const int x4 = gid & 15;
    const int y  = (gid >> 4) & 63;
    const int t  = gid >> 10;        // (b*3+slot)*192 + c, 0..9215
    const int c  = t % CF;
    const int bs = t / CF;           // b*3+slot, 0..47
    const int* bb = bbox + bs * 4;
    const int mr = bb[0], h = bb[1], mc = bb[2], w = bb[3];
    const int r = mr + ((y * h) >> 6);
    const int bimg = bs / 3;
    const float* row = feat + (((size_t)bimg * CF + c) * HH + r) * WW_;
    const int x = x4 * 4;
    float4 v;
    v.x = row[mc + (((x + 0) * w) >> 6)];
    v.y = row[mc + (((x + 1) * w) >> 6)];
    v.z = row[mc + (((x + 2) * w) >> 6)];
    v.w = row[mc + (((x + 3) * w) >> 6)];
    ((float4*)out)[gid] = v;
}

// ---------------------------------------------------------------------------

extern "C" void kernel_launch(void* const* d_in, const int* in_sizes, int n_in,
                              void* d_out, int out_size, void* d_ws, size_t ws_size,
                              hipStream_t stream) {
    const float* prob = (const float*)d_in[0];   // [16,1,128,128]
    const float* feat = (const float*)d_in[1];   // [16,192,128,128]
    float* out = (float*)d_out;                  // [16,576,64,64]

    char* ws = (char*)d_ws;
    const size_t SEG = (size_t)NB * HW * 4;      // 1 MB per array
    int*   cnt   = (int*)(ws + 0 * SEG);
    float* conf  = (float*)(ws + 1 * SEG);
    int*   minr  = (int*)(ws + 2 * SEG);
    int*   maxr  = (int*)(ws + 3 * SEG);
    int*   minc  = (int*)(ws + 4 * SEG);
    int*   maxc  = (int*)(ws + 5 * SEG);
    int*   maxid = (int*)(ws + 6 * SEG);
    int*   bbox  = (int*)(ws + 7 * SEG);         // [16][3][4] ints

    hipLaunchKernelGGL(ccl_stats_kernel, dim3(NB), dim3(1024), 0, stream,
                       prob, cnt, conf, minr, maxr, minc, maxc, maxid);
    hipLaunchKernelGGL(select_kernel, dim3(NB), dim3(256), 0, stream,
                       cnt, conf, minr, maxr, minc, maxc, maxid, bbox);
    const int total4 = NB * 3 * CF * H2 * (W2 / 4);   // 9,437,184
    hipLaunchKernelGGL(crop_kernel, dim3(total4 / 256), dim3(256), 0, stream,
                       feat, bbox, out);
}

// Round 2
// 497.881 us; speedup vs baseline: 1.0137x; 1.0137x over previous
//
#include <hip/hip_runtime.h>
#include <limits.h>

#define HH 128
#define WW_ 128
#define HW 16384
#define NB 16
#define CF 192
#define H2 64
#define W2 64
#define RLCAP 4096

typedef float vf4 __attribute__((ext_vector_type(4)));

// ---------------------------------------------------------------------------
// Union-find helpers (LDS parent array; nodes are run-start pixel ids).
// Links always go high->low index, so chains strictly decrease -> path
// halving under concurrency is safe and terminating.
// ---------------------------------------------------------------------------

__device__ inline int uf_find(int* par, int x) {
    volatile int* vp = (volatile int*)par;
    int p = vp[x];
    while (p != x) {
        int g = vp[p];
        vp[x] = g;      // path halving: writes an ancestor, safe under races
        x = g;
        p = vp[x];
    }
    return x;
}

__device__ inline void uf_union(int* par, int a, int b) {
    int ra = uf_find(par, a);
    int rb = uf_find(par, b);
    while (ra != rb) {
        if (ra < rb) { int t = ra; ra = rb; rb = t; }   // link larger -> smaller
        int old = atomicCAS(&par[ra], ra, rb);
        if (old == ra) return;
        ra = uf_find(par, old);
        rb = uf_find(par, rb);
    }
}

// ---------------------------------------------------------------------------
// 128-bit row mask helpers (lo = cols 0..63, hi = cols 64..127)
// ---------------------------------------------------------------------------

__device__ inline int getbit2(unsigned long long lo, unsigned long long hi, int c) {
    return (int)(((c < 64) ? (lo >> c) : (hi >> (c - 64))) & 1ULL);
}

__device__ inline int leading_ones(unsigned long long v) {
    unsigned long long nv = ~v;
    return (nv == 0ULL) ? 64 : __clzll(nv);
}

__device__ inline int trailing_ones(unsigned long long v) {
    unsigned long long nv = ~v;
    return (nv == 0ULL) ? 64 : (__ffsll(nv) - 1);
}

// column of the start of the fg run containing column c (bit c must be set)
__device__ inline int run_start_col(unsigned long long lo, unsigned long long hi, int c) {
    if (c < 64) {
        int ones = leading_ones(lo << (63 - c));   // consecutive ones ending at c
        return c - ones + 1;
    }
    int ones = leading_ones(hi << (127 - c));
    int rs = c - ones + 1;
    if (rs == 64) rs -= leading_ones(lo);          // run extends across the 64 boundary
    return rs;
}

// column of the end of the fg run containing column c (bit c must be set)
__device__ inline int run_end_col(unsigned long long lo, unsigned long long hi, int c) {
    if (c >= 64) {
        return c + trailing_ones(hi >> (c - 64)) - 1;
    }
    int e = c + trailing_ones(lo >> c) - 1;
    if (e == 63) e += trailing_ones(hi);           // run extends across the 64 boundary
    return e;
}

// ---------------------------------------------------------------------------
// Kernel 1: one block per image. Run-based union-find CCL + per-run stats.
// ---------------------------------------------------------------------------

__global__ __launch_bounds__(1024) void ccl_stats_kernel(
    const float* __restrict__ prob,
    int* __restrict__ cnt, float* __restrict__ conf,
    int* __restrict__ maxr, int* __restrict__ maxc, int* __restrict__ maxid,
    int* __restrict__ minr, int* __restrict__ minc,
    int* __restrict__ nroots, int* __restrict__ rootlist)
{
    __shared__ int parent[HW];
    __shared__ unsigned long long rowmask[HH][2];
    const int b = blockIdx.x;
    const int tid = threadIdx.x;
    const float* p = prob + (size_t)b * HW;
    const int base = b * HW;

    // P0: build per-row fg bitmasks. Each wave's 64 lanes cover exactly half
    // a row (coalesced float loads), ballot gives the 64-bit mask directly.
    #pragma unroll
    for (int k = 0; k < HW / 1024; ++k) {
        int i = k * 1024 + tid;
        bool fg = p[i] > 0.5f;
        unsigned long long m = __ballot(fg);
        if ((tid & 63) == 0) rowmask[i >> 7][(i >> 6) & 1] = m;
    }
    __syncthreads();

    // P1: parent self-init at run starts only
    #pragma unroll
    for (int k = 0; k < HW / 1024; ++k) {
        int i = k * 1024 + tid, r = i >> 7, c = i & 127;
        unsigned long long lo = rowmask[r][0], hi = rowmask[r][1];
        if (getbit2(lo, hi, c) && (c == 0 || !getbit2(lo, hi, c - 1)))
            parent[i] = i;
    }
    __syncthreads();

    // P2: vertical unions between run starts, fired only at the leftmost
    // contact pixel of each (run, upper-run) pair (dedup via l/ul/up/ur bits)
    for (int k = 0; k < HW / 1024; ++k) {
        int i = k * 1024 + tid, r = i >> 7, c = i & 127;
        if (r == 0) continue;
        unsigned long long lo = rowmask[r][0], hi = rowmask[r][1];
        if (!getbit2(lo, hi, c)) continue;
        unsigned long long ulo = rowmask[r - 1][0], uhi = rowmask[r - 1][1];
        int l  = (c > 0)   ? getbit2(lo, hi, c - 1) : 0;
        int rt = (c < 127) ? getbit2(lo, hi, c + 1) : 0;
        int up = getbit2(ulo, uhi, c);
        int ul = (c > 0)   ? getbit2(ulo, uhi, c - 1) : 0;
        int ur = (c < 127) ? getbit2(ulo, uhi, c + 1) : 0;
        bool u1 = up && !(l && ul);
        bool u2 = !up && ul && !l;
        bool u3 = !up && ur && !rt;
        if (u1 | u2 | u3) {
            int rs_i = (r << 7) + run_start_col(lo, hi, c);
            int ru = (r - 1) << 7;
            if (u1) uf_union(parent, rs_i, ru + run_start_col(ulo, uhi, c));
            if (u2) uf_union(parent, rs_i, ru + run_start_col(ulo, uhi, c - 1));
            if (u3) uf_union(parent, rs_i, ru + run_start_col(ulo, uhi, c + 1));
        }
    }
    __syncthreads();

    // P3: flatten — every run start points directly at its root
    for (int k = 0; k < HW / 1024; ++k) {
        int i = k * 1024 + tid, r = i >> 7, c = i & 127;
        unsigned long long lo = rowmask[r][0], hi = rowmask[r][1];
        if (getbit2(lo, hi, c) && (c == 0 || !getbit2(lo, hi, c - 1)))
            parent[i] = uf_find(parent, i);
    }
    __syncthreads();

    // P4: per-run stats, one atomic flush per run. maxid stored as idx+1 so a
    // zero-init is a valid identity for atomicMax (ordering is preserved).
    for (int k = 0; k < HW / 1024; ++k) {
        int i = k * 1024 + tid, r = i >> 7, c = i & 127;
        unsigned long long lo = rowmask[r][0], hi = rowmask[r][1];
        if (!(getbit2(lo, hi, c) && (c == 0 || !getbit2(lo, hi, c - 1)))) continue;
        int e = run_end_col(lo, hi, c);
        int root = parent[i];
        float s = 0.f;
        for (int j = c; j <= e; ++j) s += p[(r << 7) + j];
        atomicAdd(&cnt[base + root], e - c + 1);
        atomicAdd(&conf[base + root], s);
        atomicMin(&minr[base + root], r);
        atomicMax(&maxr[base + root], r);
        atomicMin(&minc[base + root], c);
        atomicMax(&maxc[base + root], e);
        atomicMax(&maxid[base + root], (r << 7) + e + 1);
        if (root == i) {                     // exactly once per component
            int idx = atomicAdd(&nroots[b], 1);
            if (idx < RLCAP) rootlist[b * RLCAP + idx] = i;
        }
    }
}

// ---------------------------------------------------------------------------
// Kernel 2: one block per image. Scan the compact root list, top-3 by
// (mean_conf desc, segment-id asc), K-dependent duplication, write 3 bboxes.
// ---------------------------------------------------------------------------

__global__ __launch_bounds__(256) void select_kernel(
    const int* __restrict__ cnt, const float* __restrict__ conf,
    const int* __restrict__ maxr, const int* __restrict__ maxc,
    const int* __restrict__ maxid,
    const int* __restrict__ minr, const int* __restrict__ minc,
    const int* __restrict__ nroots, const int* __restrict__ rootlist,
    int* __restrict__ bbox)
{
    const int b = blockIdx.x;
    const int tid = threadIdx.x;
    const int base = b * HW;
    int n = nroots[b];
    if (n > RLCAP) n = RLCAP;

    float s0 = -INFINITY, s1 = -INFINITY, s2 = -INFINITY;
    int id0 = INT_MAX, id1 = INT_MAX, id2 = INT_MAX;
    int r0 = -1, r1 = -1, r2 = -1;

    for (int i = tid; i < n; i += 256) {
        int rr = rootlist[b * RLCAP + i];
        int c = cnt[base + rr];
        float s = conf[base + rr] / (float)c;
        int id = maxid[base + rr];
        if (s > s0 || (s == s0 && id < id0)) {
            s2 = s1; id2 = id1; r2 = r1;
            s1 = s0; id1 = id0; r1 = r0;
            s0 = s; id0 = id; r0 = rr;
        } else if (s > s1 || (s == s1 && id < id1)) {
            s2 = s1; id2 = id1; r2 = r1;
            s1 = s; id1 = id; r1 = rr;
        } else if (s > s2 || (s == s2 && id < id2)) {
            s2 = s; id2 = id; r2 = rr;
        }
    }

    __shared__ float ss[256 * 3];
    __shared__ int sid[256 * 3];
    __shared__ int sr[256 * 3];
    ss[tid * 3 + 0] = s0; sid[tid * 3 + 0] = id0; sr[tid * 3 + 0] = r0;
    ss[tid * 3 + 1] = s1; sid[tid * 3 + 1] = id1; sr[tid * 3 + 1] = r1;
    ss[tid * 3 + 2] = s2; sid[tid * 3 + 2] = id2; sr[tid * 3 + 2] = r2;
    __syncthreads();

    if (tid == 0) {
        float t0 = -INFINITY, t1 = -INFINITY, t2 = -INFINITY;
        int tid0 = INT_MAX, tid1 = INT_MAX, tid2 = INT_MAX;
        int tr0 = -1, tr1 = -1, tr2 = -1;
        int lim = 256 * 3; if (n < 256) lim = n * 3;  // harmless cap
        for (int t = 0; t < lim; ++t) {
            float s = ss[t]; int id = sid[t]; int rr = sr[t];
            if (rr < 0) continue;
            if (s > t0 || (s == t0 && id < tid0)) {
                t2 = t1; tid2 = tid1; tr2 = tr1;
                t1 = t0; tid1 = tid0; tr1 = tr0;
                t0 = s; tid0 = id; tr0 = rr;
            } else if (s > t1 || (s == t1 && id < tid1)) {
                t2 = t1; tid2 = tid1; tr2 = tr1;
                t1 = s; tid1 = id; tr1 = rr;
            } else if (s > t2 || (s == t2 && id < tid2)) {
                t2 = s; tid2 = id; tr2 = rr;
            }
        }
        int K = n;
        int roots[3];
        if (K >= 3)      { roots[0] = tr0; roots[1] = tr1; roots[2] = tr2; }
        else if (K == 2) { roots[0] = tr0; roots[1] = tr0; roots[2] = tr1; }
        else             { roots[0] = tr0; roots[1] = tr0; roots[2] = tr0; }
        for (int slot = 0; slot < 3; ++slot) {
            int mr, h, mc, w;
            if (K == 0) { mr = 0; h = HH; mc = 0; w = WW_; }
            else {
                int rt2 = roots[slot];
                mr = minr[base + rt2];
                h  = maxr[base + rt2] + 1 - mr;
                mc = minc[base + rt2];
                w  = maxc[base + rt2] + 1 - mc;
            }
            int* o = bbox + (b * 3 + slot) * 4;
            o[0] = mr; o[1] = h; o[2] = mc; o[3] = w;
        }
    }
}

// ---------------------------------------------------------------------------
// Kernel 3: nearest-neighbor crop-resize gather. One float4 store per thread.
// out[b, slot*192+c, y, x] = feat[b, c, mr + (y*h)>>6, mc + (x*w)>>6]
// ---------------------------------------------------------------------------

__global__ __launch_bounds__(256) void crop_kernel(
    const float* __restrict__ feat, const int* __restrict__ bbox,
    float* __restrict__ out)
{
    const int gid = blockIdx.x * 256 + threadIdx.x;   // 9,437,184 total
    const int x4 = gid & 15;
    const int y  = (gid >> 4) & 63;
    const int t  = gid >> 10;        // (b*3+slot)*192 + c, 0..9215
    const int c  = t % CF;
    const int bs = t / CF;           // b*3+slot, 0..47
    const int* bb = bbox + bs * 4;
    const int mr = bb[0], h = bb[1], mc = bb[2], w = bb[3];
    const int r = mr + ((y * h) >> 6);
    const int bimg = bs / 3;
    const float* row = feat + (((size_t)bimg * CF + c) * HH + r) * WW_;
    const int x = x4 * 4;
    vf4 v;
    v.x = row[mc + (((x + 0) * w) >> 6)];
    v.y = row[mc + (((x + 1) * w) >> 6)];
    v.z = row[mc + (((x + 2) * w) >> 6)];
    v.w = row[mc + (((x + 3) * w) >> 6)];
    __builtin_nontemporal_store(v, (vf4*)out + gid);  // streaming store, skip L2 alloc
}

// ---------------------------------------------------------------------------

extern "C" void kernel_launch(void* const* d_in, const int* in_sizes, int n_in,
                              void* d_out, int out_size, void* d_ws, size_t ws_size,
                              hipStream_t stream) {
    const float* prob = (const float*)d_in[0];   // [16,1,128,128]
    const float* feat = (const float*)d_in[1];   // [16,192,128,128]
    float* out = (float*)d_out;                  // [16,576,64,64]

    char* ws = (char*)d_ws;
    const size_t SEG = (size_t)NB * HW * 4;      // 1 MB per stats array
    int*   cnt      = (int*)(ws + 0 * SEG);      // memset 0
    float* conf     = (float*)(ws + 1 * SEG);    // memset 0
    int*   maxr     = (int*)(ws + 2 * SEG);      // memset 0 (values >= 0)
    int*   maxc     = (int*)(ws + 3 * SEG);      // memset 0
    int*   maxid    = (int*)(ws + 4 * SEG);      // memset 0 (stored as idx+1)
    int*   nroots   = (int*)(ws + 5 * SEG);      // 64 B, memset 0
    int*   bbox     = (int*)(ws + 5 * SEG + 1024);      // 768 B, overwritten
    int*   minr     = (int*)(ws + 5 * SEG + 4096);      // memset 0x7F
    int*   minc     = (int*)(ws + 6 * SEG + 4096);      // memset 0x7F
    int*   rootlist = (int*)(ws + 7 * SEG + 4096);      // 256 KB, no init

    hipMemsetAsync(ws, 0, 5 * SEG + 4096, stream);
    hipMemsetAsync(ws + 5 * SEG + 4096, 0x7F, 2 * SEG, stream);

    hipLaunchKernelGGL(ccl_stats_kernel, dim3(NB), dim3(1024), 0, stream,
                       prob, cnt, conf, maxr, maxc, maxid, minr, minc,
                       nroots, rootlist);
    hipLaunchKernelGGL(select_kernel, dim3(NB), dim3(256), 0, stream,
                       cnt, conf, maxr, maxc, maxid, minr, minc,
                       nroots, rootlist, bbox);
    const int total4 = NB * 3 * CF * H2 * (W2 / 4);   // 9,437,184
    hipLaunchKernelGGL(crop_kernel, dim3(total4 / 256), dim3(256), 0, stream,
                       feat, bbox, out);
}